// Round 3
// baseline (864.454 us; speedup 1.0000x reference)
//
#include <hip/hip_runtime.h>

// GeodesicShooting on [160^3,3] f32.
// Internal layout SoA [3][D][H][W]; identity grid folded analytically (s = idx + 79.5*v).
// All kernels process 4 consecutive x-voxels per thread (float4), taps fully unrolled.

constexpr int W = 160, H = 160, D = 160;
constexpr int NVOX = W * H * D;          // 4,096,000
constexpr int NT4  = NVOX / 4;           // 1,024,000 threads per pass
constexpr int NSTEPS = 6;
constexpr float HSC = 79.5f;             // 0.5*(W-1)

__device__ __forceinline__ int iclamp(int v, int lo, int hi) {
    return v < lo ? lo : (v > hi ? hi : v);
}

// ---- blur along z: AoS velocity -> SoA, 9 taps, zero-pad via masked weights ----
__global__ void blur_z_aos2soa(const float* __restrict__ in, float* __restrict__ out,
                               const float* __restrict__ gk)
{
    int i = blockIdx.x * blockDim.x + threadIdx.x;
    if (i >= NT4) return;
    int f = i * 4;
    int x = f % W;
    int r = f / W;
    int y = r % H;
    int z = r / H;

    float kw[9];
#pragma unroll
    for (int t = 0; t < 9; ++t) kw[t] = gk[t];

    float ax[4] = {0,0,0,0}, ay[4] = {0,0,0,0}, az[4] = {0,0,0,0};
#pragma unroll
    for (int t = 0; t < 9; ++t) {
        int zz = z + t - 4;
        float wgt = (zz >= 0 && zz < D) ? kw[t] : 0.0f;
        int zc = iclamp(zz, 0, D - 1);
        const float4* p = (const float4*)(in + (size_t)((zc * H + y) * W + x) * 3);
        float4 a = p[0], b = p[1], c = p[2];   // 4 voxels AoS = 12 floats
        ax[0] = fmaf(wgt, a.x, ax[0]); ay[0] = fmaf(wgt, a.y, ay[0]); az[0] = fmaf(wgt, a.z, az[0]);
        ax[1] = fmaf(wgt, a.w, ax[1]); ay[1] = fmaf(wgt, b.x, ay[1]); az[1] = fmaf(wgt, b.y, az[1]);
        ax[2] = fmaf(wgt, b.z, ax[2]); ay[2] = fmaf(wgt, b.w, ay[2]); az[2] = fmaf(wgt, c.x, az[2]);
        ax[3] = fmaf(wgt, c.y, ax[3]); ay[3] = fmaf(wgt, c.z, ay[3]); az[3] = fmaf(wgt, c.w, az[3]);
    }
    *(float4*)(out + f)            = make_float4(ax[0], ax[1], ax[2], ax[3]);
    *(float4*)(out + NVOX + f)     = make_float4(ay[0], ay[1], ay[2], ay[3]);
    *(float4*)(out + 2 * NVOX + f) = make_float4(az[0], az[1], az[2], az[3]);
}

// ---- blur along y: SoA -> SoA ----
__global__ void blur_y_soa(const float* __restrict__ in, float* __restrict__ out,
                           const float* __restrict__ gk)
{
    int i = blockIdx.x * blockDim.x + threadIdx.x;
    if (i >= NT4) return;
    int f = i * 4;
    int x = f % W;
    int r = f / W;
    int y = r % H;
    int z = r / H;

    float kw[9];
#pragma unroll
    for (int t = 0; t < 9; ++t) kw[t] = gk[t];

    float acc[3][4] = {{0,0,0,0},{0,0,0,0},{0,0,0,0}};
#pragma unroll
    for (int t = 0; t < 9; ++t) {
        int yy = y + t - 4;
        float wgt = (yy >= 0 && yy < H) ? kw[t] : 0.0f;
        int yc = iclamp(yy, 0, H - 1);
        int base = (z * H + yc) * W + x;
#pragma unroll
        for (int cmp = 0; cmp < 3; ++cmp) {
            float4 a = *(const float4*)(in + (size_t)cmp * NVOX + base);
            acc[cmp][0] = fmaf(wgt, a.x, acc[cmp][0]);
            acc[cmp][1] = fmaf(wgt, a.y, acc[cmp][1]);
            acc[cmp][2] = fmaf(wgt, a.z, acc[cmp][2]);
            acc[cmp][3] = fmaf(wgt, a.w, acc[cmp][3]);
        }
    }
#pragma unroll
    for (int cmp = 0; cmp < 3; ++cmp)
        *(float4*)(out + (size_t)cmp * NVOX + f) =
            make_float4(acc[cmp][0], acc[cmp][1], acc[cmp][2], acc[cmp][3]);
}

// ---- blur along x (+ 2^-6 scale): 12-float window -> 4 outputs per comp ----
__global__ void blur_x_soa_scale(const float* __restrict__ in, float* __restrict__ out,
                                 const float* __restrict__ gk, float scale)
{
    int i = blockIdx.x * blockDim.x + threadIdx.x;
    if (i >= NT4) return;
    int f = i * 4;
    int x = f % W;
    int rowbase = f - x;                  // (z*H+y)*W

    float kw[9];
#pragma unroll
    for (int t = 0; t < 9; ++t) kw[t] = gk[t];

    int xa = (x == 0) ? 0 : x - 4;        // clamped aligned window starts (values masked)
    int xc = (x == W - 4) ? x : x + 4;

#pragma unroll
    for (int cmp = 0; cmp < 3; ++cmp) {
        const float* p = in + (size_t)cmp * NVOX + rowbase;
        float4 A = *(const float4*)(p + xa);
        float4 B = *(const float4*)(p + x);
        float4 C = *(const float4*)(p + xc);
        float wv[12] = {A.x, A.y, A.z, A.w, B.x, B.y, B.z, B.w, C.x, C.y, C.z, C.w};
#pragma unroll
        for (int pp = 0; pp < 12; ++pp) {
            int xi = x - 4 + pp;
            if (xi < 0 || xi >= W) wv[pp] = 0.0f;   // zero padding
        }
        float o[4];
#pragma unroll
        for (int j = 0; j < 4; ++j) {
            float s = 0.f;
#pragma unroll
            for (int t = 0; t < 9; ++t) s = fmaf(kw[t], wv[j + t], s);
            o[j] = s * scale;
        }
        *(float4*)(out + (size_t)cmp * NVOX + f) = make_float4(o[0], o[1], o[2], o[3]);
    }
}

// ---- one scaling-and-squaring step: out = v + trilerp(v, id + v) ----
template<bool AOS_OUT>
__global__ void step_soa(const float* __restrict__ v, float* __restrict__ out)
{
    int i = blockIdx.x * blockDim.x + threadIdx.x;
    if (i >= NT4) return;
    int f = i * 4;
    int x = f % W;
    int r = f / W;
    int y = r % H;
    int z = r / H;

    float4 vx4 = *(const float4*)(v + f);
    float4 vy4 = *(const float4*)(v + NVOX + f);
    float4 vz4 = *(const float4*)(v + 2 * NVOX + f);
    float vx[4] = {vx4.x, vx4.y, vx4.z, vx4.w};
    float vy[4] = {vy4.x, vy4.y, vy4.z, vy4.w};
    float vz[4] = {vz4.x, vz4.y, vz4.z, vz4.w};

    float res[3][4];
#pragma unroll
    for (int j = 0; j < 4; ++j) {
        float sx = fmaf(vx[j], HSC, (float)(x + j));
        float sy = fmaf(vy[j], HSC, (float)y);
        float sz = fmaf(vz[j], HSC, (float)z);

        float fx = floorf(sx), fy = floorf(sy), fz = floorf(sz);
        int x0 = (int)fx, y0 = (int)fy, z0 = (int)fz;
        float wx1 = sx - fx, wy1 = sy - fy, wz1 = sz - fz;
        float wx0 = 1.f - wx1, wy0 = 1.f - wy1, wz0 = 1.f - wz1;

        wx0 *= (x0     >= 0 && x0     < W) ? 1.f : 0.f;
        wx1 *= (x0 + 1 >= 0 && x0 + 1 < W) ? 1.f : 0.f;
        wy0 *= (y0     >= 0 && y0     < H) ? 1.f : 0.f;
        wy1 *= (y0 + 1 >= 0 && y0 + 1 < H) ? 1.f : 0.f;
        wz0 *= (z0     >= 0 && z0     < D) ? 1.f : 0.f;
        wz1 *= (z0 + 1 >= 0 && z0 + 1 < D) ? 1.f : 0.f;

        int xc0 = iclamp(x0, 0, W - 1), xc1 = iclamp(x0 + 1, 0, W - 1);
        int yc0 = iclamp(y0, 0, H - 1), yc1 = iclamp(y0 + 1, 0, H - 1);
        int zc0 = iclamp(z0, 0, D - 1), zc1 = iclamp(z0 + 1, 0, D - 1);

        int r00 = (zc0 * H + yc0) * W;
        int r01 = (zc0 * H + yc1) * W;
        int r10 = (zc1 * H + yc0) * W;
        int r11 = (zc1 * H + yc1) * W;

        float w00 = wz0 * wy0, w01 = wz0 * wy1, w10 = wz1 * wy0, w11 = wz1 * wy1;

#pragma unroll
        for (int cmp = 0; cmp < 3; ++cmp) {
            const float* p = v + (size_t)cmp * NVOX;
            res[cmp][j] =
                w00 * (wx0 * p[r00 + xc0] + wx1 * p[r00 + xc1]) +
                w01 * (wx0 * p[r01 + xc0] + wx1 * p[r01 + xc1]) +
                w10 * (wx0 * p[r10 + xc0] + wx1 * p[r10 + xc1]) +
                w11 * (wx0 * p[r11 + xc0] + wx1 * p[r11 + xc1]);
        }
    }

    if (AOS_OUT) {
        // AoS: voxel f+j, comp c at (f+j)*3+c ; 48B per thread, 16B-aligned
        float o[12];
#pragma unroll
        for (int j = 0; j < 4; ++j) {
            o[j * 3 + 0] = vx[j] + res[0][j];
            o[j * 3 + 1] = vy[j] + res[1][j];
            o[j * 3 + 2] = vz[j] + res[2][j];
        }
        float4* q = (float4*)(out + (size_t)f * 3);
        q[0] = make_float4(o[0], o[1], o[2],  o[3]);
        q[1] = make_float4(o[4], o[5], o[6],  o[7]);
        q[2] = make_float4(o[8], o[9], o[10], o[11]);
    } else {
        *(float4*)(out + f) =
            make_float4(vx[0] + res[0][0], vx[1] + res[0][1], vx[2] + res[0][2], vx[3] + res[0][3]);
        *(float4*)(out + NVOX + f) =
            make_float4(vy[0] + res[1][0], vy[1] + res[1][1], vy[2] + res[1][2], vy[3] + res[1][3]);
        *(float4*)(out + 2 * NVOX + f) =
            make_float4(vz[0] + res[2][0], vz[1] + res[2][1], vz[2] + res[2][2], vz[3] + res[2][3]);
    }
}

extern "C" void kernel_launch(void* const* d_in, const int* in_sizes, int n_in,
                              void* d_out, int out_size, void* d_ws, size_t ws_size,
                              hipStream_t stream)
{
    const float* vel = (const float*)d_in[0];
    const float* gk  = (const float*)d_in[2];   // klen == 9 (sigma=1, trunc=4)

    float* OUT = (float*)d_out;
    float* WS  = (float*)d_ws;

    const int threads = 256;
    const int blocks = NT4 / threads;           // 4000, exact
    const float scale = 1.0f / (float)(1 << NSTEPS);

    blur_z_aos2soa  <<<blocks, threads, 0, stream>>>(vel, OUT, gk);
    blur_y_soa      <<<blocks, threads, 0, stream>>>(OUT, WS, gk);
    blur_x_soa_scale<<<blocks, threads, 0, stream>>>(WS, OUT, gk, scale);

    step_soa<false><<<blocks, threads, 0, stream>>>(OUT, WS);
    step_soa<false><<<blocks, threads, 0, stream>>>(WS, OUT);
    step_soa<false><<<blocks, threads, 0, stream>>>(OUT, WS);
    step_soa<false><<<blocks, threads, 0, stream>>>(WS, OUT);
    step_soa<false><<<blocks, threads, 0, stream>>>(OUT, WS);
    step_soa<true ><<<blocks, threads, 0, stream>>>(WS, OUT);   // final: AoS into d_out
}

// Round 4
// 322.937 us; speedup vs baseline: 2.6768x; 2.6768x over previous
//
#include <hip/hip_runtime.h>

// GeodesicShooting on [160^3,3] f32, all-AoS layout (R1 structure — proven cache
// locality with 1 voxel/thread, 16000 fine-grained blocks).
//   1) separable Gaussian blur (9 taps, zero-pad), scale 2^-6 fused into last pass
//   2) 6x scaling-and-squaring: v <- v + trilinear_sample(v, id + v)
// Identity grid folded analytically: sample_x = x + 79.5 * vx.

constexpr int W = 160, H = 160, D = 160;
constexpr int NVOX = W * H * D;           // 4,096,000
constexpr int NSTEPS = 6;
constexpr float HSC = 79.5f;              // 0.5*(W-1)

__device__ __forceinline__ int iclamp(int v, int lo, int hi) {
    return v < lo ? lo : (v > hi ? hi : v);
}

// ---- blur along one axis, AoS -> AoS, 9 taps hard-unrolled, branchless ----
// axis coord = (i / div) % len ; neighbor step = strideVox voxels
__global__ void blur_axis_kernel(const float* __restrict__ in, float* __restrict__ out,
                                 const float* __restrict__ kern,
                                 int len, int div, int strideVox, float scale)
{
    int i = blockIdx.x * blockDim.x + threadIdx.x;
    if (i >= NVOX) return;
    int c = (i / div) % len;

    float kw[9];
#pragma unroll
    for (int t = 0; t < 9; ++t) kw[t] = kern[t];

    float ax = 0.f, ay = 0.f, az = 0.f;
#pragma unroll
    for (int t = 0; t < 9; ++t) {
        int cc = c + t - 4;
        bool ok = (cc >= 0) && (cc < len);
        float w = ok ? kw[t] : 0.0f;          // masked weight (zero padding)
        int off = ok ? (t - 4) * strideVox : 0; // clamped offset keeps load in-bounds
        const float* p = in + (size_t)(i + off) * 3;
        ax = fmaf(w, p[0], ax);
        ay = fmaf(w, p[1], ay);
        az = fmaf(w, p[2], az);
    }
    float* q = out + (size_t)i * 3;
    q[0] = ax * scale;
    q[1] = ay * scale;
    q[2] = az * scale;
}

// ---- one scaling-and-squaring step: out = v + trilerp(v, id + v), AoS ----
__global__ void step_kernel(const float* __restrict__ v, float* __restrict__ out)
{
    int i = blockIdx.x * blockDim.x + threadIdx.x;
    if (i >= NVOX) return;
    int x = i % W;
    int t = i / W;
    int y = t % H;
    int z = t / H;

    const float* pv = v + (size_t)i * 3;
    float vx = pv[0], vy = pv[1], vz = pv[2];

    // identity grid folded analytically
    float sx = fmaf(vx, HSC, (float)x);
    float sy = fmaf(vy, HSC, (float)y);
    float sz = fmaf(vz, HSC, (float)z);

    float fx = floorf(sx), fy = floorf(sy), fz = floorf(sz);
    int x0 = (int)fx, y0 = (int)fy, z0 = (int)fz;
    float wx1 = sx - fx, wy1 = sy - fy, wz1 = sz - fz;
    float wx0 = 1.f - wx1, wy0 = 1.f - wy1, wz0 = 1.f - wz1;

    // zeros-padding: mask weights per axis, clamp indices for in-bounds loads
    wx0 *= (x0     >= 0 && x0     < W) ? 1.f : 0.f;
    wx1 *= (x0 + 1 >= 0 && x0 + 1 < W) ? 1.f : 0.f;
    wy0 *= (y0     >= 0 && y0     < H) ? 1.f : 0.f;
    wy1 *= (y0 + 1 >= 0 && y0 + 1 < H) ? 1.f : 0.f;
    wz0 *= (z0     >= 0 && z0     < D) ? 1.f : 0.f;
    wz1 *= (z0 + 1 >= 0 && z0 + 1 < D) ? 1.f : 0.f;

    int xc0 = iclamp(x0, 0, W - 1), xc1 = iclamp(x0 + 1, 0, W - 1);
    int yc0 = iclamp(y0, 0, H - 1), yc1 = iclamp(y0 + 1, 0, H - 1);
    int zc0 = iclamp(z0, 0, D - 1), zc1 = iclamp(z0 + 1, 0, D - 1);

    // 8 corner voxel indices
    int idx[8];
    idx[0] = (zc0 * H + yc0) * W + xc0;
    idx[1] = (zc0 * H + yc0) * W + xc1;
    idx[2] = (zc0 * H + yc1) * W + xc0;
    idx[3] = (zc0 * H + yc1) * W + xc1;
    idx[4] = (zc1 * H + yc0) * W + xc0;
    idx[5] = (zc1 * H + yc0) * W + xc1;
    idx[6] = (zc1 * H + yc1) * W + xc0;
    idx[7] = (zc1 * H + yc1) * W + xc1;

    // issue ALL 8 corner loads (12B each) before any arithmetic -> 8-deep MLP
    float c[8][3];
#pragma unroll
    for (int k = 0; k < 8; ++k) {
        const float* p = v + (size_t)idx[k] * 3;
        c[k][0] = p[0];
        c[k][1] = p[1];
        c[k][2] = p[2];
    }

    float w8[8];
    w8[0] = wz0 * wy0 * wx0;
    w8[1] = wz0 * wy0 * wx1;
    w8[2] = wz0 * wy1 * wx0;
    w8[3] = wz0 * wy1 * wx1;
    w8[4] = wz1 * wy0 * wx0;
    w8[5] = wz1 * wy0 * wx1;
    w8[6] = wz1 * wy1 * wx0;
    w8[7] = wz1 * wy1 * wx1;

    float r0 = vx, r1 = vy, r2 = vz;
#pragma unroll
    for (int k = 0; k < 8; ++k) {
        r0 = fmaf(w8[k], c[k][0], r0);
        r1 = fmaf(w8[k], c[k][1], r1);
        r2 = fmaf(w8[k], c[k][2], r2);
    }

    float* q = out + (size_t)i * 3;
    q[0] = r0;
    q[1] = r1;
    q[2] = r2;
}

extern "C" void kernel_launch(void* const* d_in, const int* in_sizes, int n_in,
                              void* d_out, int out_size, void* d_ws, size_t ws_size,
                              hipStream_t stream)
{
    const float* vel = (const float*)d_in[0];
    // d_in[1] (identity grid) folded analytically
    const float* gk  = (const float*)d_in[2];   // 9 taps (sigma=1, trunc=4)

    float* OUT = (float*)d_out;
    float* WS  = (float*)d_ws;                  // one [NVOX,3] f32 buffer (49.2 MB)

    const int threads = 256;
    const int blocks = (NVOX + threads - 1) / threads;   // 16000
    const float scale = 1.0f / (float)(1 << NSTEPS);     // 2^-6

    // blur: z axis, y axis, x axis (scale fused into last pass)
    blur_axis_kernel<<<blocks, threads, 0, stream>>>(vel, OUT, gk, D, W * H, W * H, 1.0f);
    blur_axis_kernel<<<blocks, threads, 0, stream>>>(OUT, WS, gk, H, W, W, 1.0f);
    blur_axis_kernel<<<blocks, threads, 0, stream>>>(WS, OUT, gk, W, 1, 1, scale);

    // 6 squaring steps: OUT -> WS -> OUT -> ... -> OUT
    step_kernel<<<blocks, threads, 0, stream>>>(OUT, WS);
    step_kernel<<<blocks, threads, 0, stream>>>(WS, OUT);
    step_kernel<<<blocks, threads, 0, stream>>>(OUT, WS);
    step_kernel<<<blocks, threads, 0, stream>>>(WS, OUT);
    step_kernel<<<blocks, threads, 0, stream>>>(OUT, WS);
    step_kernel<<<blocks, threads, 0, stream>>>(WS, OUT);
}

// Round 5
// 242.499 us; speedup vs baseline: 3.5648x; 1.3317x over previous
//
#include <hip/hip_runtime.h>

// GeodesicShooting on [160^3,3] f32, AoS layout.
//   1) separable Gaussian blur (9 taps, zero-pad), scale 2^-6 fused into x pass
//      z/y passes: rolling register window (each input read ~1.25x, no cache reliance)
//      x pass: 4 voxels/thread, contiguous float4 window
//   2) 6x scaling-and-squaring: v <- v + trilerp(v, id + v), 8-corner MLP gather
// Identity grid folded analytically: sample_x = x + 79.5 * vx.

constexpr int W = 160, H = 160, D = 160;
constexpr int NVOX = W * H * D;            // 4,096,000
constexpr int NSTEPS = 6;
constexpr float HSC = 79.5f;               // 0.5*(W-1)
constexpr int SEG = 32;                    // rolling-window segment length

__device__ __forceinline__ int iclamp(int v, int lo, int hi) {
    return v < lo ? lo : (v > hi ? hi : v);
}

// ---- blur along z: rolling 9-plane register window, thread = (x,y) column segment ----
__global__ void blur_z_roll(const float* __restrict__ in, float* __restrict__ out,
                            const float* __restrict__ gk)
{
    int tid = blockIdx.x * blockDim.x + threadIdx.x;   // 128000 threads
    int x = tid % W;
    int r = tid / W;
    int y = r % H;
    int seg = r / H;                                    // 0..4
    int z0 = seg * SEG;

    const size_t PS = (size_t)W * H * 3;                // plane stride in floats
    size_t colBase = ((size_t)y * W + x) * 3;

    float kw[9];
#pragma unroll
    for (int t = 0; t < 9; ++t) kw[t] = gk[t];

    float win[9][3];
    // preload planes z0-4 .. z0+3 into slots 0..7
#pragma unroll
    for (int j = 0; j < 8; ++j) {
        int zz = z0 - 4 + j;
        bool ok = (zz >= 0) && (zz < D);
        const float* p = in + (size_t)iclamp(zz, 0, D - 1) * PS + colBase;
        win[j][0] = ok ? p[0] : 0.f;
        win[j][1] = ok ? p[1] : 0.f;
        win[j][2] = ok ? p[2] : 0.f;
    }
#pragma unroll
    for (int t = 0; t < SEG; ++t) {
        int zz = z0 + t + 4;
        bool ok = zz < D;
        const float* p = in + (size_t)iclamp(zz, 0, D - 1) * PS + colBase;
        int wi = (t + 8) % 9;
        win[wi][0] = ok ? p[0] : 0.f;
        win[wi][1] = ok ? p[1] : 0.f;
        win[wi][2] = ok ? p[2] : 0.f;

        float a0 = 0.f, a1 = 0.f, a2 = 0.f;
#pragma unroll
        for (int k = 0; k < 9; ++k) {
            int s = (t + k) % 9;
            a0 = fmaf(kw[k], win[s][0], a0);
            a1 = fmaf(kw[k], win[s][1], a1);
            a2 = fmaf(kw[k], win[s][2], a2);
        }
        float* q = out + (size_t)(z0 + t) * PS + colBase;
        q[0] = a0; q[1] = a1; q[2] = a2;
    }
}

// ---- blur along y: rolling window, thread = (x,z) column segment ----
__global__ void blur_y_roll(const float* __restrict__ in, float* __restrict__ out,
                            const float* __restrict__ gk)
{
    int tid = blockIdx.x * blockDim.x + threadIdx.x;   // 128000 threads
    int x = tid % W;
    int r = tid / W;
    int z = r % D;
    int seg = r / D;                                    // 0..4
    int y0 = seg * SEG;

    const size_t RS = (size_t)W * 3;                    // row stride in floats
    size_t base = ((size_t)z * H * W + x) * 3;          // y=0 element of this column

    float kw[9];
#pragma unroll
    for (int t = 0; t < 9; ++t) kw[t] = gk[t];

    float win[9][3];
#pragma unroll
    for (int j = 0; j < 8; ++j) {
        int yy = y0 - 4 + j;
        bool ok = (yy >= 0) && (yy < H);
        const float* p = in + base + (size_t)iclamp(yy, 0, H - 1) * RS;
        win[j][0] = ok ? p[0] : 0.f;
        win[j][1] = ok ? p[1] : 0.f;
        win[j][2] = ok ? p[2] : 0.f;
    }
#pragma unroll
    for (int t = 0; t < SEG; ++t) {
        int yy = y0 + t + 4;
        bool ok = yy < H;
        const float* p = in + base + (size_t)iclamp(yy, 0, H - 1) * RS;
        int wi = (t + 8) % 9;
        win[wi][0] = ok ? p[0] : 0.f;
        win[wi][1] = ok ? p[1] : 0.f;
        win[wi][2] = ok ? p[2] : 0.f;

        float a0 = 0.f, a1 = 0.f, a2 = 0.f;
#pragma unroll
        for (int k = 0; k < 9; ++k) {
            int s = (t + k) % 9;
            a0 = fmaf(kw[k], win[s][0], a0);
            a1 = fmaf(kw[k], win[s][1], a1);
            a2 = fmaf(kw[k], win[s][2], a2);
        }
        float* q = out + base + (size_t)(y0 + t) * RS;
        q[0] = a0; q[1] = a1; q[2] = a2;
    }
}

// ---- blur along x (+ 2^-6 scale): 4 voxels/thread, 9 float4 window loads ----
__global__ void blur_x_vec4(const float* __restrict__ in, float* __restrict__ out,
                            const float* __restrict__ gk, float scale)
{
    int tid = blockIdx.x * blockDim.x + threadIdx.x;    // 1,024,000 threads
    if (tid >= NVOX / 4) return;
    int nx4 = W / 4;                                     // 40
    int x0 = (tid % nx4) * 4;
    int row = tid / nx4;                                 // (z*H + y)
    size_t rowBase = (size_t)row * W * 3;                // floats

    float kw[9];
#pragma unroll
    for (int t = 0; t < 9; ++t) kw[t] = gk[t];

    // window: voxels x0-4 .. x0+7 -> 36 floats = 9 float4 (16B-aligned: x0 % 4 == 0)
    long f0 = (long)rowBase + (long)(x0 - 4) * 3;        // may be negative at x0==0
    const long maxF4 = (long)NVOX * 3 - 4;
    float wv[36];
#pragma unroll
    for (int k = 0; k < 9; ++k) {
        long a = f0 + 4 * k;
        a = a < 0 ? 0 : (a > maxF4 ? maxF4 : a);
        float4 v4 = *(const float4*)(in + a);
        wv[4 * k + 0] = v4.x; wv[4 * k + 1] = v4.y;
        wv[4 * k + 2] = v4.z; wv[4 * k + 3] = v4.w;
    }
    // zero-pad mask: voxel slot m covers x = x0-4+m
#pragma unroll
    for (int m = 0; m < 12; ++m) {
        int xi = x0 - 4 + m;
        if (xi < 0 || xi >= W) { wv[3 * m] = 0.f; wv[3 * m + 1] = 0.f; wv[3 * m + 2] = 0.f; }
    }

    float o[12];
#pragma unroll
    for (int j = 0; j < 4; ++j) {
#pragma unroll
        for (int c = 0; c < 3; ++c) {
            float s = 0.f;
#pragma unroll
            for (int t = 0; t < 9; ++t) s = fmaf(kw[t], wv[3 * (j + t) + c], s);
            o[3 * j + c] = s * scale;
        }
    }
    float4* q = (float4*)(out + rowBase + (size_t)x0 * 3);
    q[0] = make_float4(o[0], o[1], o[2],  o[3]);
    q[1] = make_float4(o[4], o[5], o[6],  o[7]);
    q[2] = make_float4(o[8], o[9], o[10], o[11]);
}

// ---- one scaling-and-squaring step: out = v + trilerp(v, id + v), AoS ----
// XCD-aware block swizzle: 16000 blocks % 8 == 0 -> contiguous chunk per XCD.
__global__ void step_kernel(const float* __restrict__ v, float* __restrict__ out)
{
    int b = blockIdx.x;
    int bs = (b & 7) * 2000 + (b >> 3);                 // bijective XCD swizzle
    int i = bs * blockDim.x + threadIdx.x;
    int x = i % W;
    int t = i / W;
    int y = t % H;
    int z = t / H;

    const float* pv = v + (size_t)i * 3;
    float vx = pv[0], vy = pv[1], vz = pv[2];

    float sx = fmaf(vx, HSC, (float)x);
    float sy = fmaf(vy, HSC, (float)y);
    float sz = fmaf(vz, HSC, (float)z);

    float fx = floorf(sx), fy = floorf(sy), fz = floorf(sz);
    int x0 = (int)fx, y0 = (int)fy, z0 = (int)fz;
    float wx1 = sx - fx, wy1 = sy - fy, wz1 = sz - fz;
    float wx0 = 1.f - wx1, wy0 = 1.f - wy1, wz0 = 1.f - wz1;

    wx0 *= (x0     >= 0 && x0     < W) ? 1.f : 0.f;
    wx1 *= (x0 + 1 >= 0 && x0 + 1 < W) ? 1.f : 0.f;
    wy0 *= (y0     >= 0 && y0     < H) ? 1.f : 0.f;
    wy1 *= (y0 + 1 >= 0 && y0 + 1 < H) ? 1.f : 0.f;
    wz0 *= (z0     >= 0 && z0     < D) ? 1.f : 0.f;
    wz1 *= (z0 + 1 >= 0 && z0 + 1 < D) ? 1.f : 0.f;

    int xc0 = iclamp(x0, 0, W - 1), xc1 = iclamp(x0 + 1, 0, W - 1);
    int yc0 = iclamp(y0, 0, H - 1), yc1 = iclamp(y0 + 1, 0, H - 1);
    int zc0 = iclamp(z0, 0, D - 1), zc1 = iclamp(z0 + 1, 0, D - 1);

    int idx[8];
    idx[0] = (zc0 * H + yc0) * W + xc0;
    idx[1] = (zc0 * H + yc0) * W + xc1;
    idx[2] = (zc0 * H + yc1) * W + xc0;
    idx[3] = (zc0 * H + yc1) * W + xc1;
    idx[4] = (zc1 * H + yc0) * W + xc0;
    idx[5] = (zc1 * H + yc0) * W + xc1;
    idx[6] = (zc1 * H + yc1) * W + xc0;
    idx[7] = (zc1 * H + yc1) * W + xc1;

    float c[8][3];
#pragma unroll
    for (int k = 0; k < 8; ++k) {
        const float* p = v + (size_t)idx[k] * 3;
        c[k][0] = p[0];
        c[k][1] = p[1];
        c[k][2] = p[2];
    }

    float w8[8];
    w8[0] = wz0 * wy0 * wx0;
    w8[1] = wz0 * wy0 * wx1;
    w8[2] = wz0 * wy1 * wx0;
    w8[3] = wz0 * wy1 * wx1;
    w8[4] = wz1 * wy0 * wx0;
    w8[5] = wz1 * wy0 * wx1;
    w8[6] = wz1 * wy1 * wx0;
    w8[7] = wz1 * wy1 * wx1;

    float r0 = vx, r1 = vy, r2 = vz;
#pragma unroll
    for (int k = 0; k < 8; ++k) {
        r0 = fmaf(w8[k], c[k][0], r0);
        r1 = fmaf(w8[k], c[k][1], r1);
        r2 = fmaf(w8[k], c[k][2], r2);
    }

    float* q = out + (size_t)i * 3;
    q[0] = r0;
    q[1] = r1;
    q[2] = r2;
}

extern "C" void kernel_launch(void* const* d_in, const int* in_sizes, int n_in,
                              void* d_out, int out_size, void* d_ws, size_t ws_size,
                              hipStream_t stream)
{
    const float* vel = (const float*)d_in[0];
    // d_in[1] (identity grid) folded analytically
    const float* gk  = (const float*)d_in[2];   // 9 taps

    float* OUT = (float*)d_out;
    float* WS  = (float*)d_ws;                  // one [NVOX,3] f32 buffer

    const int threads = 256;
    const int rollBlocks = (W * H * (D / SEG)) / threads;   // 500
    const int x4Blocks   = (NVOX / 4) / threads;            // 4000
    const int stepBlocks = NVOX / threads;                  // 16000
    const float scale = 1.0f / (float)(1 << NSTEPS);        // 2^-6

    blur_z_roll<<<rollBlocks, threads, 0, stream>>>(vel, OUT, gk);
    blur_y_roll<<<rollBlocks, threads, 0, stream>>>(OUT, WS, gk);
    blur_x_vec4<<<x4Blocks,  threads, 0, stream>>>(WS, OUT, gk, scale);

    step_kernel<<<stepBlocks, threads, 0, stream>>>(OUT, WS);
    step_kernel<<<stepBlocks, threads, 0, stream>>>(WS, OUT);
    step_kernel<<<stepBlocks, threads, 0, stream>>>(OUT, WS);
    step_kernel<<<stepBlocks, threads, 0, stream>>>(WS, OUT);
    step_kernel<<<stepBlocks, threads, 0, stream>>>(OUT, WS);
    step_kernel<<<stepBlocks, threads, 0, stream>>>(WS, OUT);
}

// Round 6
// 242.177 us; speedup vs baseline: 3.5695x; 1.0013x over previous
//
#include <hip/hip_runtime.h>

// GeodesicShooting on [160^3,3] f32, AoS layout.
//   1) separable Gaussian blur (9 taps, zero-pad), scale 2^-6 fused into x pass
//      z/y passes: STATIC register window — thread owns 16-output segment, loads
//      all 24 window values/comp up-front (72 independent loads, huge MLP)
//      x pass: 4 voxels/thread, contiguous float4 window
//   2) 6x scaling-and-squaring: v <- v + trilerp(v, id + v), 8-corner MLP gather
// Identity grid folded analytically: sample_x = x + 79.5 * vx.

constexpr int W = 160, H = 160, D = 160;
constexpr int NVOX = W * H * D;            // 4,096,000
constexpr int NSTEPS = 6;
constexpr float HSC = 79.5f;               // 0.5*(W-1)
constexpr int SEG = 16;                    // outputs per thread in z/y passes
constexpr int WIN = SEG + 8;               // 24 window values per component

__device__ __forceinline__ int iclamp(int v, int lo, int hi) {
    return v < lo ? lo : (v > hi ? hi : v);
}

// ---- blur along z: static 24-value window, thread = (x,y) column segment ----
__global__ void blur_z_win(const float* __restrict__ in, float* __restrict__ out,
                           const float* __restrict__ gk)
{
    int tid = blockIdx.x * blockDim.x + threadIdx.x;   // 256,000 threads
    int x = tid % W;
    int r = tid / W;
    int y = r % H;
    int seg = r / H;                                    // 0..9
    int z0 = seg * SEG;

    const size_t PS = (size_t)W * H * 3;                // plane stride (floats)
    size_t colBase = ((size_t)y * W + x) * 3;

    float kw[9];
#pragma unroll
    for (int t = 0; t < 9; ++t) kw[t] = gk[t];

    float win[WIN][3];
    if (z0 >= 4 && z0 + SEG + 4 <= D) {                 // interior: wave-uniform fast path
        const float* p0 = in + (size_t)(z0 - 4) * PS + colBase;
#pragma unroll
        for (int j = 0; j < WIN; ++j) {
            const float* p = p0 + (size_t)j * PS;
            win[j][0] = p[0]; win[j][1] = p[1]; win[j][2] = p[2];
        }
    } else {                                            // boundary: masked + clamped
#pragma unroll
        for (int j = 0; j < WIN; ++j) {
            int zz = z0 - 4 + j;
            bool ok = (zz >= 0) && (zz < D);
            const float* p = in + (size_t)iclamp(zz, 0, D - 1) * PS + colBase;
            win[j][0] = ok ? p[0] : 0.f;
            win[j][1] = ok ? p[1] : 0.f;
            win[j][2] = ok ? p[2] : 0.f;
        }
    }

#pragma unroll
    for (int t = 0; t < SEG; ++t) {
        float a0 = 0.f, a1 = 0.f, a2 = 0.f;
#pragma unroll
        for (int k = 0; k < 9; ++k) {
            a0 = fmaf(kw[k], win[t + k][0], a0);
            a1 = fmaf(kw[k], win[t + k][1], a1);
            a2 = fmaf(kw[k], win[t + k][2], a2);
        }
        float* q = out + (size_t)(z0 + t) * PS + colBase;
        q[0] = a0; q[1] = a1; q[2] = a2;
    }
}

// ---- blur along y: static window, thread = (x,z) column segment ----
__global__ void blur_y_win(const float* __restrict__ in, float* __restrict__ out,
                           const float* __restrict__ gk)
{
    int tid = blockIdx.x * blockDim.x + threadIdx.x;   // 256,000 threads
    int x = tid % W;
    int r = tid / W;
    int z = r % D;
    int seg = r / D;                                    // 0..9
    int y0 = seg * SEG;

    const size_t RS = (size_t)W * 3;                    // row stride (floats)
    size_t base = ((size_t)z * H * W + x) * 3;

    float kw[9];
#pragma unroll
    for (int t = 0; t < 9; ++t) kw[t] = gk[t];

    float win[WIN][3];
    if (y0 >= 4 && y0 + SEG + 4 <= H) {
        const float* p0 = in + base + (size_t)(y0 - 4) * RS;
#pragma unroll
        for (int j = 0; j < WIN; ++j) {
            const float* p = p0 + (size_t)j * RS;
            win[j][0] = p[0]; win[j][1] = p[1]; win[j][2] = p[2];
        }
    } else {
#pragma unroll
        for (int j = 0; j < WIN; ++j) {
            int yy = y0 - 4 + j;
            bool ok = (yy >= 0) && (yy < H);
            const float* p = in + base + (size_t)iclamp(yy, 0, H - 1) * RS;
            win[j][0] = ok ? p[0] : 0.f;
            win[j][1] = ok ? p[1] : 0.f;
            win[j][2] = ok ? p[2] : 0.f;
        }
    }

#pragma unroll
    for (int t = 0; t < SEG; ++t) {
        float a0 = 0.f, a1 = 0.f, a2 = 0.f;
#pragma unroll
        for (int k = 0; k < 9; ++k) {
            a0 = fmaf(kw[k], win[t + k][0], a0);
            a1 = fmaf(kw[k], win[t + k][1], a1);
            a2 = fmaf(kw[k], win[t + k][2], a2);
        }
        float* q = out + base + (size_t)(y0 + t) * RS;
        q[0] = a0; q[1] = a1; q[2] = a2;
    }
}

// ---- blur along x (+ 2^-6 scale): 4 voxels/thread, 9 float4 window loads ----
__global__ void blur_x_vec4(const float* __restrict__ in, float* __restrict__ out,
                            const float* __restrict__ gk, float scale)
{
    int tid = blockIdx.x * blockDim.x + threadIdx.x;    // 1,024,000 threads
    if (tid >= NVOX / 4) return;
    int nx4 = W / 4;                                     // 40
    int x0 = (tid % nx4) * 4;
    int row = tid / nx4;                                 // (z*H + y)
    size_t rowBase = (size_t)row * W * 3;

    float kw[9];
#pragma unroll
    for (int t = 0; t < 9; ++t) kw[t] = gk[t];

    long f0 = (long)rowBase + (long)(x0 - 4) * 3;        // may be negative at x0==0
    const long maxF4 = (long)NVOX * 3 - 4;
    float wv[36];
#pragma unroll
    for (int k = 0; k < 9; ++k) {
        long a = f0 + 4 * k;
        a = a < 0 ? 0 : (a > maxF4 ? maxF4 : a);
        float4 v4 = *(const float4*)(in + a);
        wv[4 * k + 0] = v4.x; wv[4 * k + 1] = v4.y;
        wv[4 * k + 2] = v4.z; wv[4 * k + 3] = v4.w;
    }
#pragma unroll
    for (int m = 0; m < 12; ++m) {
        int xi = x0 - 4 + m;
        if (xi < 0 || xi >= W) { wv[3 * m] = 0.f; wv[3 * m + 1] = 0.f; wv[3 * m + 2] = 0.f; }
    }

    float o[12];
#pragma unroll
    for (int j = 0; j < 4; ++j) {
#pragma unroll
        for (int c = 0; c < 3; ++c) {
            float s = 0.f;
#pragma unroll
            for (int t = 0; t < 9; ++t) s = fmaf(kw[t], wv[3 * (j + t) + c], s);
            o[3 * j + c] = s * scale;
        }
    }
    float4* q = (float4*)(out + rowBase + (size_t)x0 * 3);
    q[0] = make_float4(o[0], o[1], o[2],  o[3]);
    q[1] = make_float4(o[4], o[5], o[6],  o[7]);
    q[2] = make_float4(o[8], o[9], o[10], o[11]);
}

// ---- one scaling-and-squaring step: out = v + trilerp(v, id + v), AoS ----
__global__ void step_kernel(const float* __restrict__ v, float* __restrict__ out)
{
    int b = blockIdx.x;
    int bs = (b & 7) * 2000 + (b >> 3);                 // bijective XCD swizzle (16000 % 8 == 0)
    int i = bs * blockDim.x + threadIdx.x;
    int x = i % W;
    int t = i / W;
    int y = t % H;
    int z = t / H;

    const float* pv = v + (size_t)i * 3;
    float vx = pv[0], vy = pv[1], vz = pv[2];

    float sx = fmaf(vx, HSC, (float)x);
    float sy = fmaf(vy, HSC, (float)y);
    float sz = fmaf(vz, HSC, (float)z);

    float fx = floorf(sx), fy = floorf(sy), fz = floorf(sz);
    int x0 = (int)fx, y0 = (int)fy, z0 = (int)fz;
    float wx1 = sx - fx, wy1 = sy - fy, wz1 = sz - fz;
    float wx0 = 1.f - wx1, wy0 = 1.f - wy1, wz0 = 1.f - wz1;

    wx0 *= (x0     >= 0 && x0     < W) ? 1.f : 0.f;
    wx1 *= (x0 + 1 >= 0 && x0 + 1 < W) ? 1.f : 0.f;
    wy0 *= (y0     >= 0 && y0     < H) ? 1.f : 0.f;
    wy1 *= (y0 + 1 >= 0 && y0 + 1 < H) ? 1.f : 0.f;
    wz0 *= (z0     >= 0 && z0     < D) ? 1.f : 0.f;
    wz1 *= (z0 + 1 >= 0 && z0 + 1 < D) ? 1.f : 0.f;

    int xc0 = iclamp(x0, 0, W - 1), xc1 = iclamp(x0 + 1, 0, W - 1);
    int yc0 = iclamp(y0, 0, H - 1), yc1 = iclamp(y0 + 1, 0, H - 1);
    int zc0 = iclamp(z0, 0, D - 1), zc1 = iclamp(z0 + 1, 0, D - 1);

    int idx[8];
    idx[0] = (zc0 * H + yc0) * W + xc0;
    idx[1] = (zc0 * H + yc0) * W + xc1;
    idx[2] = (zc0 * H + yc1) * W + xc0;
    idx[3] = (zc0 * H + yc1) * W + xc1;
    idx[4] = (zc1 * H + yc0) * W + xc0;
    idx[5] = (zc1 * H + yc0) * W + xc1;
    idx[6] = (zc1 * H + yc1) * W + xc0;
    idx[7] = (zc1 * H + yc1) * W + xc1;

    float c[8][3];
#pragma unroll
    for (int k = 0; k < 8; ++k) {
        const float* p = v + (size_t)idx[k] * 3;
        c[k][0] = p[0];
        c[k][1] = p[1];
        c[k][2] = p[2];
    }

    float w8[8];
    w8[0] = wz0 * wy0 * wx0;
    w8[1] = wz0 * wy0 * wx1;
    w8[2] = wz0 * wy1 * wx0;
    w8[3] = wz0 * wy1 * wx1;
    w8[4] = wz1 * wy0 * wx0;
    w8[5] = wz1 * wy0 * wx1;
    w8[6] = wz1 * wy1 * wx0;
    w8[7] = wz1 * wy1 * wx1;

    float r0 = vx, r1 = vy, r2 = vz;
#pragma unroll
    for (int k = 0; k < 8; ++k) {
        r0 = fmaf(w8[k], c[k][0], r0);
        r1 = fmaf(w8[k], c[k][1], r1);
        r2 = fmaf(w8[k], c[k][2], r2);
    }

    float* q = out + (size_t)i * 3;
    q[0] = r0;
    q[1] = r1;
    q[2] = r2;
}

extern "C" void kernel_launch(void* const* d_in, const int* in_sizes, int n_in,
                              void* d_out, int out_size, void* d_ws, size_t ws_size,
                              hipStream_t stream)
{
    const float* vel = (const float*)d_in[0];
    // d_in[1] (identity grid) folded analytically
    const float* gk  = (const float*)d_in[2];   // 9 taps

    float* OUT = (float*)d_out;
    float* WS  = (float*)d_ws;                  // one [NVOX,3] f32 buffer

    const int threads = 256;
    const int winBlocks = (W * H * (D / SEG)) / threads;    // 1000
    const int x4Blocks  = (NVOX / 4) / threads;             // 4000
    const int stepBlocks = NVOX / threads;                  // 16000
    const float scale = 1.0f / (float)(1 << NSTEPS);        // 2^-6

    blur_z_win <<<winBlocks, threads, 0, stream>>>(vel, OUT, gk);
    blur_y_win <<<winBlocks, threads, 0, stream>>>(OUT, WS, gk);
    blur_x_vec4<<<x4Blocks, threads, 0, stream>>>(WS, OUT, gk, scale);

    step_kernel<<<stepBlocks, threads, 0, stream>>>(OUT, WS);
    step_kernel<<<stepBlocks, threads, 0, stream>>>(WS, OUT);
    step_kernel<<<stepBlocks, threads, 0, stream>>>(OUT, WS);
    step_kernel<<<stepBlocks, threads, 0, stream>>>(WS, OUT);
    step_kernel<<<stepBlocks, threads, 0, stream>>>(OUT, WS);
    step_kernel<<<stepBlocks, threads, 0, stream>>>(WS, OUT);
}

// Round 7
// 239.464 us; speedup vs baseline: 3.6099x; 1.0113x over previous
//
#include <hip/hip_runtime.h>

// GeodesicShooting on [160^3,3] f32, AoS layout.
//   1) z-blur (static 16-plane window, SEG=8, high occupancy) ->
//      fused y+x blur in LDS (one plane tile per block) with 2^-6 scale
//   2) 6x scaling-and-squaring: v <- v + trilerp(v, id + v), 8-corner MLP gather
// All kernels use bijective XCD swizzle for L2 slab locality.
// Identity grid folded analytically: sample_x = x + 79.5 * vx.
// Buffer parity: blur_z vel->WS ; blur_yx WS->OUT ; steps OUT->WS->...->OUT (6 steps).

constexpr int W = 160, H = 160, D = 160;
constexpr int NVOX = W * H * D;            // 4,096,000
constexpr int NSTEPS = 6;
constexpr float HSC = 79.5f;               // 0.5*(W-1)

constexpr int ZSEG = 8;                    // z-blur outputs per thread
constexpr int ZWIN = ZSEG + 8;             // 16 window planes

constexpr int YT = 16;                     // y outputs per block
constexpr int XT = 80;                     // x outputs per block (half row)
constexpr int YR = YT + 8;                 // 24 staged rows
constexpr int XR = XT + 8;                 // 88 staged cols

__device__ __forceinline__ int iclamp(int v, int lo, int hi) {
    return v < lo ? lo : (v > hi ? hi : v);
}

// ---- blur along z: static 16-plane window, thread = (x,y) column segment ----
__global__ void blur_z_win(const float* __restrict__ in, float* __restrict__ out,
                           const float* __restrict__ gk)
{
    int b = blockIdx.x;
    int bs = (b & 7) * 250 + (b >> 3);                 // 2000 blocks, bijective
    int tid = bs * blockDim.x + threadIdx.x;
    int x = tid % W;
    int r = tid / W;
    int y = r % H;
    int seg = r / H;                                    // 0..19
    int z0 = seg * ZSEG;

    const size_t PS = (size_t)W * H * 3;
    size_t colBase = ((size_t)y * W + x) * 3;

    float kw[9];
#pragma unroll
    for (int t = 0; t < 9; ++t) kw[t] = gk[t];

    float win[ZWIN][3];
    if (z0 >= 4 && z0 + ZSEG + 4 <= D) {                // interior fast path
        const float* p0 = in + (size_t)(z0 - 4) * PS + colBase;
#pragma unroll
        for (int j = 0; j < ZWIN; ++j) {
            const float* p = p0 + (size_t)j * PS;
            win[j][0] = p[0]; win[j][1] = p[1]; win[j][2] = p[2];
        }
    } else {
#pragma unroll
        for (int j = 0; j < ZWIN; ++j) {
            int zz = z0 - 4 + j;
            bool ok = (zz >= 0) && (zz < D);
            const float* p = in + (size_t)iclamp(zz, 0, D - 1) * PS + colBase;
            win[j][0] = ok ? p[0] : 0.f;
            win[j][1] = ok ? p[1] : 0.f;
            win[j][2] = ok ? p[2] : 0.f;
        }
    }

#pragma unroll
    for (int t = 0; t < ZSEG; ++t) {
        float a0 = 0.f, a1 = 0.f, a2 = 0.f;
#pragma unroll
        for (int k = 0; k < 9; ++k) {
            a0 = fmaf(kw[k], win[t + k][0], a0);
            a1 = fmaf(kw[k], win[t + k][1], a1);
            a2 = fmaf(kw[k], win[t + k][2], a2);
        }
        float* q = out + (size_t)(z0 + t) * PS + colBase;
        q[0] = a0; q[1] = a1; q[2] = a2;
    }
}

// ---- fused y-blur + x-blur (+ 2^-6 scale) over one plane tile ----
__global__ void blur_yx_fused(const float* __restrict__ in, float* __restrict__ out,
                              const float* __restrict__ gk, float scale)
{
    __shared__ float raw[YR][XR][3];   // 25.3 KB
    __shared__ float yb [YT][XR][3];   // 16.9 KB

    int b = blockIdx.x;
    int bs = (b & 7) * 400 + (b >> 3);                 // 3200 blocks, bijective
    int xh   = bs % 2;
    int t2   = bs / 2;
    int yseg = t2 % 10;
    int z    = t2 / 10;
    int y0 = yseg * YT;
    int x0 = xh * XT;

    float kw[9];
#pragma unroll
    for (int t = 0; t < 9; ++t) kw[t] = gk[t];

    const size_t planeBase = (size_t)z * H * W * 3;

    for (int j = threadIdx.x; j < YR * XR; j += 256) {
        int col = j % XR;
        int row = j / XR;
        int yy = y0 - 4 + row;
        int xx = x0 - 4 + col;
        bool ok = (yy >= 0) && (yy < H) && (xx >= 0) && (xx < W);
        const float* p = in + planeBase +
            ((size_t)iclamp(yy, 0, H - 1) * W + iclamp(xx, 0, W - 1)) * 3;
        raw[row][col][0] = ok ? p[0] : 0.f;
        raw[row][col][1] = ok ? p[1] : 0.f;
        raw[row][col][2] = ok ? p[2] : 0.f;
    }
    __syncthreads();

    for (int j = threadIdx.x; j < YT * XR; j += 256) {
        int col = j % XR;
        int row = j / XR;
        float a0 = 0.f, a1 = 0.f, a2 = 0.f;
#pragma unroll
        for (int k = 0; k < 9; ++k) {
            a0 = fmaf(kw[k], raw[row + k][col][0], a0);
            a1 = fmaf(kw[k], raw[row + k][col][1], a1);
            a2 = fmaf(kw[k], raw[row + k][col][2], a2);
        }
        yb[row][col][0] = a0;
        yb[row][col][1] = a1;
        yb[row][col][2] = a2;
    }
    __syncthreads();

    for (int j = threadIdx.x; j < YT * XT; j += 256) {
        int xo = j % XT;
        int yo = j / XT;
        float a0 = 0.f, a1 = 0.f, a2 = 0.f;
#pragma unroll
        for (int k = 0; k < 9; ++k) {
            a0 = fmaf(kw[k], yb[yo][xo + k][0], a0);
            a1 = fmaf(kw[k], yb[yo][xo + k][1], a1);
            a2 = fmaf(kw[k], yb[yo][xo + k][2], a2);
        }
        float* q = out + planeBase + ((size_t)(y0 + yo) * W + (x0 + xo)) * 3;
        q[0] = a0 * scale;
        q[1] = a1 * scale;
        q[2] = a2 * scale;
    }
}

// ---- one scaling-and-squaring step: out = v + trilerp(v, id + v), AoS ----
__global__ void step_kernel(const float* __restrict__ v, float* __restrict__ out)
{
    int b = blockIdx.x;
    int bs = (b & 7) * 2000 + (b >> 3);                 // bijective XCD swizzle
    int i = bs * blockDim.x + threadIdx.x;
    int x = i % W;
    int t = i / W;
    int y = t % H;
    int z = t / H;

    const float* pv = v + (size_t)i * 3;
    float vx = pv[0], vy = pv[1], vz = pv[2];

    float sx = fmaf(vx, HSC, (float)x);
    float sy = fmaf(vy, HSC, (float)y);
    float sz = fmaf(vz, HSC, (float)z);

    float fx = floorf(sx), fy = floorf(sy), fz = floorf(sz);
    int x0 = (int)fx, y0 = (int)fy, z0 = (int)fz;
    float wx1 = sx - fx, wy1 = sy - fy, wz1 = sz - fz;
    float wx0 = 1.f - wx1, wy0 = 1.f - wy1, wz0 = 1.f - wz1;

    wx0 *= (x0     >= 0 && x0     < W) ? 1.f : 0.f;
    wx1 *= (x0 + 1 >= 0 && x0 + 1 < W) ? 1.f : 0.f;
    wy0 *= (y0     >= 0 && y0     < H) ? 1.f : 0.f;
    wy1 *= (y0 + 1 >= 0 && y0 + 1 < H) ? 1.f : 0.f;
    wz0 *= (z0     >= 0 && z0     < D) ? 1.f : 0.f;
    wz1 *= (z0 + 1 >= 0 && z0 + 1 < D) ? 1.f : 0.f;

    int xc0 = iclamp(x0, 0, W - 1), xc1 = iclamp(x0 + 1, 0, W - 1);
    int yc0 = iclamp(y0, 0, H - 1), yc1 = iclamp(y0 + 1, 0, H - 1);
    int zc0 = iclamp(z0, 0, D - 1), zc1 = iclamp(z0 + 1, 0, D - 1);

    int idx[8];
    idx[0] = (zc0 * H + yc0) * W + xc0;
    idx[1] = (zc0 * H + yc0) * W + xc1;
    idx[2] = (zc0 * H + yc1) * W + xc0;
    idx[3] = (zc0 * H + yc1) * W + xc1;
    idx[4] = (zc1 * H + yc0) * W + xc0;
    idx[5] = (zc1 * H + yc0) * W + xc1;
    idx[6] = (zc1 * H + yc1) * W + xc0;
    idx[7] = (zc1 * H + yc1) * W + xc1;

    float c[8][3];
#pragma unroll
    for (int k = 0; k < 8; ++k) {
        const float* p = v + (size_t)idx[k] * 3;
        c[k][0] = p[0];
        c[k][1] = p[1];
        c[k][2] = p[2];
    }

    float w8[8];
    w8[0] = wz0 * wy0 * wx0;
    w8[1] = wz0 * wy0 * wx1;
    w8[2] = wz0 * wy1 * wx0;
    w8[3] = wz0 * wy1 * wx1;
    w8[4] = wz1 * wy0 * wx0;
    w8[5] = wz1 * wy0 * wx1;
    w8[6] = wz1 * wy1 * wx0;
    w8[7] = wz1 * wy1 * wx1;

    float r0 = vx, r1 = vy, r2 = vz;
#pragma unroll
    for (int k = 0; k < 8; ++k) {
        r0 = fmaf(w8[k], c[k][0], r0);
        r1 = fmaf(w8[k], c[k][1], r1);
        r2 = fmaf(w8[k], c[k][2], r2);
    }

    float* q = out + (size_t)i * 3;
    q[0] = r0;
    q[1] = r1;
    q[2] = r2;
}

extern "C" void kernel_launch(void* const* d_in, const int* in_sizes, int n_in,
                              void* d_out, int out_size, void* d_ws, size_t ws_size,
                              hipStream_t stream)
{
    const float* vel = (const float*)d_in[0];
    // d_in[1] (identity grid) folded analytically
    const float* gk  = (const float*)d_in[2];   // 9 taps

    float* OUT = (float*)d_out;
    float* WS  = (float*)d_ws;                  // one [NVOX,3] f32 buffer

    const int threads = 256;
    const int zBlocks   = (W * H * (D / ZSEG)) / threads;   // 2000
    const int yxBlocks  = D * (H / YT) * (W / XT);          // 3200
    const int stepBlocks = NVOX / threads;                  // 16000
    const float scale = 1.0f / (float)(1 << NSTEPS);        // 2^-6

    // blur: vel -> WS (z), WS -> OUT (y+x fused, scaled)
    blur_z_win   <<<zBlocks,  threads, 0, stream>>>(vel, WS, gk);
    blur_yx_fused<<<yxBlocks, threads, 0, stream>>>(WS, OUT, gk, scale);

    // 6 squaring steps: OUT -> WS -> OUT -> WS -> OUT -> WS -> OUT
    step_kernel<<<stepBlocks, threads, 0, stream>>>(OUT, WS);
    step_kernel<<<stepBlocks, threads, 0, stream>>>(WS, OUT);
    step_kernel<<<stepBlocks, threads, 0, stream>>>(OUT, WS);
    step_kernel<<<stepBlocks, threads, 0, stream>>>(WS, OUT);
    step_kernel<<<stepBlocks, threads, 0, stream>>>(OUT, WS);
    step_kernel<<<stepBlocks, threads, 0, stream>>>(WS, OUT);
}

// Round 8
// 239.245 us; speedup vs baseline: 3.6133x; 1.0009x over previous
//
#include <hip/hip_runtime.h>

// GeodesicShooting on [160^3,3] f32, AoS layout.
//   1) z-blur: LDS slab tile (raw[16][160] rows, 30.7 KB -> 5 blocks/CU)
//      y+x fused blur: LDS plane tile (25.3 KB -> 6 blocks/CU), 2^-6 scale fused
//   2) 6x scaling-and-squaring: v <- v + trilerp(v, id + v), 8-corner MLP gather
// All kernels use bijective XCD swizzle. Identity grid folded: s = idx + 79.5*v.
// Parity: blur_z vel->WS ; blur_yx WS->OUT ; steps OUT->WS->...->OUT (6 steps).

constexpr int W = 160, H = 160, D = 160;
constexpr int NVOX = W * H * D;            // 4,096,000
constexpr int NSTEPS = 6;
constexpr float HSC = 79.5f;               // 0.5*(W-1)

constexpr int ZT = 8;                      // z outputs per block (z-blur)
constexpr int ZR = ZT + 8;                 // 16 staged z-rows

constexpr int YT = 8;                      // y outputs per block (yx-blur)
constexpr int XT = 80;                     // x outputs per block (half row)
constexpr int YR = YT + 8;                 // 16 staged rows
constexpr int XR = XT + 8;                 // 88 staged cols

__device__ __forceinline__ int iclamp(int v, int lo, int hi) {
    return v < lo ? lo : (v > hi ? hi : v);
}

// ---- blur along z: LDS slab tile. block = (y row, 8-z slab) ----
__global__ void blur_z_lds(const float* __restrict__ in, float* __restrict__ out,
                           const float* __restrict__ gk)
{
    __shared__ float raw[ZR][W * 3];       // 30.7 KB

    int b = blockIdx.x;
    int bs = (b & 7) * 400 + (b >> 3);     // 3200 blocks, bijective
    int y    = bs % H;
    int zseg = bs / H;                     // 0..19
    int z0 = zseg * ZT;

    float kw[9];
#pragma unroll
    for (int t = 0; t < 9; ++t) kw[t] = gk[t];

    // stage 16 z-rows (each a contiguous 160*3-float run at plane stride)
    for (int j = threadIdx.x; j < ZR * W; j += 256) {
        int xx = j % W;
        int zr = j / W;
        int zz = z0 - 4 + zr;
        bool ok = (zz >= 0) && (zz < D);
        const float* p = in + ((size_t)iclamp(zz, 0, D - 1) * H + y) * W * 3 + (size_t)xx * 3;
        raw[zr][xx * 3 + 0] = ok ? p[0] : 0.f;
        raw[zr][xx * 3 + 1] = ok ? p[1] : 0.f;
        raw[zr][xx * 3 + 2] = ok ? p[2] : 0.f;
    }
    __syncthreads();

    // compute 8 x 160 outputs
    for (int j = threadIdx.x; j < ZT * W; j += 256) {
        int xo = j % W;
        int t  = j / W;
        float a0 = 0.f, a1 = 0.f, a2 = 0.f;
#pragma unroll
        for (int k = 0; k < 9; ++k) {
            a0 = fmaf(kw[k], raw[t + k][xo * 3 + 0], a0);
            a1 = fmaf(kw[k], raw[t + k][xo * 3 + 1], a1);
            a2 = fmaf(kw[k], raw[t + k][xo * 3 + 2], a2);
        }
        float* q = out + ((size_t)(z0 + t) * H + y) * W * 3 + (size_t)xo * 3;
        q[0] = a0; q[1] = a1; q[2] = a2;
    }
}

// ---- fused y-blur + x-blur (+ 2^-6 scale) over one plane tile ----
__global__ void blur_yx_fused(const float* __restrict__ in, float* __restrict__ out,
                              const float* __restrict__ gk, float scale)
{
    __shared__ float raw[YR][XR][3];   // 16.9 KB
    __shared__ float yb [YT][XR][3];   //  8.4 KB

    int b = blockIdx.x;
    int bs = (b & 7) * 800 + (b >> 3);     // 6400 blocks, bijective
    int xh   = bs % 2;
    int t2   = bs / 2;
    int yseg = t2 % 20;
    int z    = t2 / 20;
    int y0 = yseg * YT;
    int x0 = xh * XT;

    float kw[9];
#pragma unroll
    for (int t = 0; t < 9; ++t) kw[t] = gk[t];

    const size_t planeBase = (size_t)z * H * W * 3;

    for (int j = threadIdx.x; j < YR * XR; j += 256) {
        int col = j % XR;
        int row = j / XR;
        int yy = y0 - 4 + row;
        int xx = x0 - 4 + col;
        bool ok = (yy >= 0) && (yy < H) && (xx >= 0) && (xx < W);
        const float* p = in + planeBase +
            ((size_t)iclamp(yy, 0, H - 1) * W + iclamp(xx, 0, W - 1)) * 3;
        raw[row][col][0] = ok ? p[0] : 0.f;
        raw[row][col][1] = ok ? p[1] : 0.f;
        raw[row][col][2] = ok ? p[2] : 0.f;
    }
    __syncthreads();

    for (int j = threadIdx.x; j < YT * XR; j += 256) {
        int col = j % XR;
        int row = j / XR;
        float a0 = 0.f, a1 = 0.f, a2 = 0.f;
#pragma unroll
        for (int k = 0; k < 9; ++k) {
            a0 = fmaf(kw[k], raw[row + k][col][0], a0);
            a1 = fmaf(kw[k], raw[row + k][col][1], a1);
            a2 = fmaf(kw[k], raw[row + k][col][2], a2);
        }
        yb[row][col][0] = a0;
        yb[row][col][1] = a1;
        yb[row][col][2] = a2;
    }
    __syncthreads();

    for (int j = threadIdx.x; j < YT * XT; j += 256) {
        int xo = j % XT;
        int yo = j / XT;
        float a0 = 0.f, a1 = 0.f, a2 = 0.f;
#pragma unroll
        for (int k = 0; k < 9; ++k) {
            a0 = fmaf(kw[k], yb[yo][xo + k][0], a0);
            a1 = fmaf(kw[k], yb[yo][xo + k][1], a1);
            a2 = fmaf(kw[k], yb[yo][xo + k][2], a2);
        }
        float* q = out + planeBase + ((size_t)(y0 + yo) * W + (x0 + xo)) * 3;
        q[0] = a0 * scale;
        q[1] = a1 * scale;
        q[2] = a2 * scale;
    }
}

// ---- one scaling-and-squaring step: out = v + trilerp(v, id + v), AoS ----
__global__ void step_kernel(const float* __restrict__ v, float* __restrict__ out)
{
    int b = blockIdx.x;
    int bs = (b & 7) * 2000 + (b >> 3);                 // bijective XCD swizzle
    int i = bs * blockDim.x + threadIdx.x;
    int x = i % W;
    int t = i / W;
    int y = t % H;
    int z = t / H;

    const float* pv = v + (size_t)i * 3;
    float vx = pv[0], vy = pv[1], vz = pv[2];

    float sx = fmaf(vx, HSC, (float)x);
    float sy = fmaf(vy, HSC, (float)y);
    float sz = fmaf(vz, HSC, (float)z);

    float fx = floorf(sx), fy = floorf(sy), fz = floorf(sz);
    int x0 = (int)fx, y0 = (int)fy, z0 = (int)fz;
    float wx1 = sx - fx, wy1 = sy - fy, wz1 = sz - fz;
    float wx0 = 1.f - wx1, wy0 = 1.f - wy1, wz0 = 1.f - wz1;

    wx0 *= (x0     >= 0 && x0     < W) ? 1.f : 0.f;
    wx1 *= (x0 + 1 >= 0 && x0 + 1 < W) ? 1.f : 0.f;
    wy0 *= (y0     >= 0 && y0     < H) ? 1.f : 0.f;
    wy1 *= (y0 + 1 >= 0 && y0 + 1 < H) ? 1.f : 0.f;
    wz0 *= (z0     >= 0 && z0     < D) ? 1.f : 0.f;
    wz1 *= (z0 + 1 >= 0 && z0 + 1 < D) ? 1.f : 0.f;

    int xc0 = iclamp(x0, 0, W - 1), xc1 = iclamp(x0 + 1, 0, W - 1);
    int yc0 = iclamp(y0, 0, H - 1), yc1 = iclamp(y0 + 1, 0, H - 1);
    int zc0 = iclamp(z0, 0, D - 1), zc1 = iclamp(z0 + 1, 0, D - 1);

    int idx[8];
    idx[0] = (zc0 * H + yc0) * W + xc0;
    idx[1] = (zc0 * H + yc0) * W + xc1;
    idx[2] = (zc0 * H + yc1) * W + xc0;
    idx[3] = (zc0 * H + yc1) * W + xc1;
    idx[4] = (zc1 * H + yc0) * W + xc0;
    idx[5] = (zc1 * H + yc0) * W + xc1;
    idx[6] = (zc1 * H + yc1) * W + xc0;
    idx[7] = (zc1 * H + yc1) * W + xc1;

    float c[8][3];
#pragma unroll
    for (int k = 0; k < 8; ++k) {
        const float* p = v + (size_t)idx[k] * 3;
        c[k][0] = p[0];
        c[k][1] = p[1];
        c[k][2] = p[2];
    }

    float w8[8];
    w8[0] = wz0 * wy0 * wx0;
    w8[1] = wz0 * wy0 * wx1;
    w8[2] = wz0 * wy1 * wx0;
    w8[3] = wz0 * wy1 * wx1;
    w8[4] = wz1 * wy0 * wx0;
    w8[5] = wz1 * wy0 * wx1;
    w8[6] = wz1 * wy1 * wx0;
    w8[7] = wz1 * wy1 * wx1;

    float r0 = vx, r1 = vy, r2 = vz;
#pragma unroll
    for (int k = 0; k < 8; ++k) {
        r0 = fmaf(w8[k], c[k][0], r0);
        r1 = fmaf(w8[k], c[k][1], r1);
        r2 = fmaf(w8[k], c[k][2], r2);
    }

    float* q = out + (size_t)i * 3;
    q[0] = r0;
    q[1] = r1;
    q[2] = r2;
}

extern "C" void kernel_launch(void* const* d_in, const int* in_sizes, int n_in,
                              void* d_out, int out_size, void* d_ws, size_t ws_size,
                              hipStream_t stream)
{
    const float* vel = (const float*)d_in[0];
    // d_in[1] (identity grid) folded analytically
    const float* gk  = (const float*)d_in[2];   // 9 taps

    float* OUT = (float*)d_out;
    float* WS  = (float*)d_ws;                  // one [NVOX,3] f32 buffer

    const int threads = 256;
    const int zBlocks   = H * (D / ZT);                     // 3200
    const int yxBlocks  = D * (H / YT) * (W / XT);          // 6400
    const int stepBlocks = NVOX / threads;                  // 16000
    const float scale = 1.0f / (float)(1 << NSTEPS);        // 2^-6

    // blur: vel -> WS (z), WS -> OUT (y+x fused, scaled)
    blur_z_lds   <<<zBlocks,  threads, 0, stream>>>(vel, WS, gk);
    blur_yx_fused<<<yxBlocks, threads, 0, stream>>>(WS, OUT, gk, scale);

    // 6 squaring steps: OUT -> WS -> OUT -> WS -> OUT -> WS -> OUT
    step_kernel<<<stepBlocks, threads, 0, stream>>>(OUT, WS);
    step_kernel<<<stepBlocks, threads, 0, stream>>>(WS, OUT);
    step_kernel<<<stepBlocks, threads, 0, stream>>>(OUT, WS);
    step_kernel<<<stepBlocks, threads, 0, stream>>>(WS, OUT);
    step_kernel<<<stepBlocks, threads, 0, stream>>>(OUT, WS);
    step_kernel<<<stepBlocks, threads, 0, stream>>>(WS, OUT);
}